// Round 7
// baseline (388.589 us; speedup 1.0000x reference)
//
#include <hip/hip_runtime.h>
#include <hip/hip_bf16.h>

#define NN 100000
#define NE 1600000
#define NBK 196          // buckets of 512 nodes: ceil(100000/512)

typedef __attribute__((ext_vector_type(8))) short bf16x8;
typedef __attribute__((ext_vector_type(4))) float f32x4;

__device__ __forceinline__ unsigned short f2bf(float x) {
    unsigned u = __float_as_uint(x);
    return (unsigned short)((u + 0x7fffu + ((u >> 16) & 1u)) >> 16);
}
__device__ __forceinline__ float bflo(unsigned v) { return __uint_as_float(v << 16); }
__device__ __forceinline__ float bfhi(unsigned v) { return __uint_as_float(v & 0xffff0000u); }

#define ACCV(A, v) do { \
    A[0] += bflo((v).x); A[1] += bfhi((v).x); \
    A[2] += bflo((v).y); A[3] += bfhi((v).y); \
    A[4] += bflo((v).z); A[5] += bfhi((v).z); \
    A[6] += bflo((v).w); A[7] += bfhi((v).w); } while (0)

// drain remaining edges [e, end) of one node into accumulator A (16/4/tail granularity)
#define DRAIN(A, e, end) do { \
    for (; e + 15 < end; e += 16) { \
        int c0 = csr[e + g], c1 = csr[e + 4 + g], c2 = csr[e + 8 + g], c3 = csr[e + 12 + g]; \
        uint4 w0 = *(const uint4*)(hb + (unsigned)c0 + l16); \
        uint4 w1 = *(const uint4*)(hb + (unsigned)c1 + l16); \
        uint4 w2 = *(const uint4*)(hb + (unsigned)c2 + l16); \
        uint4 w3 = *(const uint4*)(hb + (unsigned)c3 + l16); \
        ACCV(A, w0); ACCV(A, w1); ACCV(A, w2); ACCV(A, w3); } \
    for (; e + 3 < end; e += 4) { \
        int c = csr[e + g]; \
        uint4 w = *(const uint4*)(hb + (unsigned)c + l16); \
        ACCV(A, w); } \
    { int rem = end - e; \
      if (g < rem) { \
        int c = csr[e + g]; \
        uint4 w = *(const uint4*)(hb + (unsigned)c + l16); \
        ACCV(A, w); } } \
} while (0)

// ---------------- cast x (f32) -> bf16 ----------------
__global__ void cast_x(const float* __restrict__ x, unsigned short* __restrict__ h, int n) {
    int i = (blockIdx.x * blockDim.x + threadIdx.x) * 4;
    if (i >= n) return;
    float4 v = *(const float4*)(x + i);
    unsigned out0 = ((unsigned)f2bf(v.y) << 16) | f2bf(v.x);
    unsigned out1 = ((unsigned)f2bf(v.w) << 16) | f2bf(v.z);
    *(uint2*)(h + i) = make_uint2(out0, out1);
}

// ---------------- bucket histogram (196 buckets, LDS-first) ----------------
__global__ __launch_bounds__(256) void hist_buck(const int* __restrict__ dst, int* __restrict__ bhist) {
    __shared__ int h[NBK];
    int t = threadIdx.x;
    if (t < NBK) h[t] = 0;
    __syncthreads();
    int base = blockIdx.x * 4096;
#pragma unroll
    for (int i = 0; i < 16; ++i) {
        int e = base + t + i * 256;
        if (e < NE) atomicAdd(&h[dst[e] >> 9], 1);
    }
    __syncthreads();
    if (t < NBK && h[t]) atomicAdd(&bhist[t], h[t]);
}

// ------- scan buckets -> bbase (exclusive, bbase[NBK]=NE) + init gcur + row_ptr[NN] -------
__global__ void scan_buck(const int* __restrict__ bhist, int* __restrict__ bbase,
                          int* __restrict__ gcur, int* __restrict__ row_ptr) {
    __shared__ int s[256];
    int t = threadIdx.x;
    int v = (t < NBK) ? bhist[t] : 0;
    s[t] = v;
    __syncthreads();
    for (int off = 1; off < 256; off <<= 1) {
        int u = (t >= off) ? s[t - off] : 0;
        __syncthreads();
        s[t] += u;
        __syncthreads();
    }
    int ex = s[t] - v;
    if (t <= NBK) bbase[t] = ex;          // bbase[NBK] == NE
    if (t < NBK) gcur[t * 16] = ex;
    if (t == 0) row_ptr[NN] = NE;
}

// ------- block-local counting sort; contiguous runs per (block,bucket) -------
__global__ __launch_bounds__(256) void sort_scatter(const int* __restrict__ src,
                                                    const int* __restrict__ dst,
                                                    int* __restrict__ gcur,
                                                    unsigned* __restrict__ pairs) {
    __shared__ int bcnt[NBK], gbase[NBK], lcur[NBK];
    int t = threadIdx.x;
    if (t < NBK) { bcnt[t] = 0; lcur[t] = 0; }
    __syncthreads();
    int base = blockIdx.x * 4096;
#pragma unroll
    for (int i = 0; i < 16; ++i) {
        int e = base + t + i * 256;
        if (e < NE) atomicAdd(&bcnt[dst[e] >> 9], 1);
    }
    __syncthreads();
    if (t < NBK) gbase[t] = atomicAdd(&gcur[t * 16], bcnt[t]);
    __syncthreads();
#pragma unroll
    for (int i = 0; i < 16; ++i) {
        int e = base + t + i * 256;
        if (e < NE) {
            int d = dst[e];
            int b = d >> 9;
            int p = atomicAdd(&lcur[b], 1);
            pairs[gbase[b] + p] = ((unsigned)src[e] << 9) | (unsigned)(d & 511);
        }
    }
}

// ------- per bucket: node hist + scan -> row_ptr/inv_deg, then place edges -> csr -------
// csr stores src*256 (byte offset into 256B bf16 h rows).
__global__ __launch_bounds__(512) void bucket_place(const unsigned* __restrict__ pairs,
                                                    const int* __restrict__ bbase,
                                                    int* __restrict__ row_ptr,
                                                    float* __restrict__ inv_deg,
                                                    int* __restrict__ csr) {
    __shared__ int hist[512], sc[512], cur[512];
    int b = blockIdx.x, t = threadIdx.x;
    hist[t] = 0;
    __syncthreads();
    int beg = bbase[b], end = bbase[b + 1];
    for (int i = beg + t; i < end; i += 512) atomicAdd(&hist[pairs[i] & 511u], 1);
    __syncthreads();
    int deg = hist[t];
    sc[t] = deg;
    __syncthreads();
    for (int off = 1; off < 512; off <<= 1) {
        int u = (t >= off) ? sc[t - off] : 0;
        __syncthreads();
        sc[t] += u;
        __syncthreads();
    }
    int ex = sc[t] - deg;
    int node = b * 512 + t;
    if (node < NN) {
        row_ptr[node] = beg + ex;
        inv_deg[node] = 1.0f / (float)max(deg, 1);
    }
    cur[t] = beg + ex;
    __syncthreads();
    for (int i = beg + t; i < end; i += 512) {
        unsigned p = pairs[i];
        int pos = atomicAdd(&cur[p & 511u], 1);
        csr[pos] = (int)(p >> 9) << 8;   // src * 256 bytes
    }
}

// ------- pack all 3 layers' [W_self; W_neigh] into MFMA B-fragment bf16 layouts -------
// layout: wp[((kstep*NF + nf)*64 + lane)*8 + j], k = kstep*32 + (lane>>4)*8 + j, n = nf*16 + (lane&15)
__global__ void pack_w_all(const float* __restrict__ Ws0, const float* __restrict__ Wn0,
                           const float* __restrict__ Ws1, const float* __restrict__ Wn1,
                           const float* __restrict__ Ws2, const float* __restrict__ Wn2,
                           unsigned short* __restrict__ wp0, unsigned short* __restrict__ wp1,
                           unsigned short* __restrict__ wp2) {
    int idx = blockIdx.x * blockDim.x + threadIdx.x;
    const float *Ws, *Wn;
    unsigned short* wp;
    int Ncols, NF, local;
    if (idx < 32768)       { Ws = Ws0; Wn = Wn0; wp = wp0; Ncols = 128; NF = 8; local = idx; }
    else if (idx < 65536)  { Ws = Ws1; Wn = Wn1; wp = wp1; Ncols = 128; NF = 8; local = idx - 32768; }
    else if (idx < 77824)  { Ws = Ws2; Wn = Wn2; wp = wp2; Ncols = 47;  NF = 3; local = idx - 65536; }
    else return;
    int j = local & 7;
    int lane = (local >> 3) & 63;
    int fid = local >> 9;          // kstep*NF + nf
    int nf = fid % NF;
    int kstep = fid / NF;
    int k = kstep * 32 + (lane >> 4) * 8 + j;
    int n = nf * 16 + (lane & 15);
    float v = 0.f;
    if (n < Ncols) v = (k < 128) ? Ws[k * Ncols + n] : Wn[(k - 128) * Ncols + n];
    wp[local] = f2bf(v);
}

// ---- aggregate: TWO nodes per wave; 16-lane groups, dwordx4 gathers, interleaved 16+16 ----
__global__ __launch_bounds__(256) void aggregate(const unsigned* __restrict__ h32,
                                                 const int* __restrict__ csr,
                                                 const int* __restrict__ row_ptr,
                                                 const float* __restrict__ inv_deg,
                                                 unsigned* __restrict__ agg32) {
    int lane = threadIdx.x & 63;
    int wave = threadIdx.x >> 6;
    int n0 = (blockIdx.x * 4 + wave) * 2;
    if (n0 >= NN) return;
    int g = lane >> 4;          // edge subgroup 0..3
    unsigned l16 = (unsigned)(lane & 15) * 16;
    const char* hb = (const char*)h32;
    int b0  = row_ptr[n0];
    int m0  = row_ptr[n0 + 1];
    int e1e = row_ptr[n0 + 2];

    float a[8], b[8];
#pragma unroll
    for (int j = 0; j < 8; ++j) { a[j] = 0.f; b[j] = 0.f; }

    int e0 = b0, e1 = m0;
    // interleaved main loop: 8 independent dwordx4 gathers (32 rows) in flight
    while (e0 + 15 < m0 && e1 + 15 < e1e) {
        int c00 = csr[e0 + g], c01 = csr[e0 + 4 + g], c02 = csr[e0 + 8 + g], c03 = csr[e0 + 12 + g];
        int c10 = csr[e1 + g], c11 = csr[e1 + 4 + g], c12 = csr[e1 + 8 + g], c13 = csr[e1 + 12 + g];
        uint4 v00 = *(const uint4*)(hb + (unsigned)c00 + l16);
        uint4 v01 = *(const uint4*)(hb + (unsigned)c01 + l16);
        uint4 v02 = *(const uint4*)(hb + (unsigned)c02 + l16);
        uint4 v03 = *(const uint4*)(hb + (unsigned)c03 + l16);
        uint4 v10 = *(const uint4*)(hb + (unsigned)c10 + l16);
        uint4 v11 = *(const uint4*)(hb + (unsigned)c11 + l16);
        uint4 v12 = *(const uint4*)(hb + (unsigned)c12 + l16);
        uint4 v13 = *(const uint4*)(hb + (unsigned)c13 + l16);
        ACCV(a, v00); ACCV(a, v01); ACCV(a, v02); ACCV(a, v03);
        ACCV(b, v10); ACCV(b, v11); ACCV(b, v12); ACCV(b, v13);
        e0 += 16; e1 += 16;
    }
    DRAIN(a, e0, m0);
    DRAIN(b, e1, e1e);

#pragma unroll
    for (int j = 0; j < 8; ++j) {
        a[j] += __shfl_xor(a[j], 16, 64);
        a[j] += __shfl_xor(a[j], 32, 64);
        b[j] += __shfl_xor(b[j], 16, 64);
        b[j] += __shfl_xor(b[j], 32, 64);
    }
    float inv = inv_deg[n0 + ((lane >> 4) & 1)];
    if (lane < 32) {
        float r[8];
#pragma unroll
        for (int j = 0; j < 8; ++j) r[j] = ((lane < 16) ? a[j] : b[j]) * inv;
        unsigned d0 = ((unsigned)f2bf(r[1]) << 16) | f2bf(r[0]);
        unsigned d1 = ((unsigned)f2bf(r[3]) << 16) | f2bf(r[2]);
        unsigned d2 = ((unsigned)f2bf(r[5]) << 16) | f2bf(r[4]);
        unsigned d3 = ((unsigned)f2bf(r[7]) << 16) | f2bf(r[6]);
        int node = n0 + (lane >> 4);
        *(uint4*)((char*)agg32 + (size_t)node * 256 + l16) = make_uint4(d0, d1, d2, d3);
    }
}

// ---------------- fused GEMM: out = h@Wself + agg@Wneigh (K=256 via packed W) ----------------
template <int NF, bool LAST>
__global__ __launch_bounds__(256) void gemm_k(const unsigned short* __restrict__ hA,
                                              const unsigned short* __restrict__ hAgg,
                                              const unsigned short* __restrict__ wpack,
                                              unsigned short* __restrict__ hOut,
                                              float* __restrict__ fOut) {
    int lane = threadIdx.x & 63;
    int wave = threadIdx.x >> 6;
    int aRow = blockIdx.x * 64 + wave * 16 + (lane & 15);
    int kgrp = (lane >> 4) * 8;

    f32x4 acc[NF];
#pragma unroll
    for (int f = 0; f < NF; ++f)
#pragma unroll
        for (int q = 0; q < 4; ++q) acc[f][q] = 0.f;

    bool inb = (aRow < NN);
#pragma unroll
    for (int half = 0; half < 2; ++half) {
        const unsigned short* A = half ? hAgg : hA;
#pragma unroll
        for (int ks = 0; ks < 4; ++ks) {
            bf16x8 afrag;
            if (inb) {
                afrag = *(const bf16x8*)(A + (size_t)aRow * 128 + ks * 32 + kgrp);
            } else {
#pragma unroll
                for (int j = 0; j < 8; ++j) afrag[j] = 0;
            }
            int kstep = half * 4 + ks;
#pragma unroll
            for (int nf = 0; nf < NF; ++nf) {
                bf16x8 b = *(const bf16x8*)(wpack + (((kstep * NF + nf) * 64) + lane) * 8);
                acc[nf] = __builtin_amdgcn_mfma_f32_16x16x32_bf16(afrag, b, acc[nf], 0, 0, 0);
            }
        }
    }

    int col0 = lane & 15;
    int rBase = blockIdx.x * 64 + wave * 16 + (lane >> 4) * 4;
#pragma unroll
    for (int nf = 0; nf < NF; ++nf) {
        int col = nf * 16 + col0;
        if (LAST) {
            if (col < 47) {
#pragma unroll
                for (int q = 0; q < 4; ++q) {
                    int row = rBase + q;
                    if (row < NN) fOut[(size_t)row * 47 + col] = acc[nf][q];
                }
            }
        } else {
#pragma unroll
            for (int q = 0; q < 4; ++q) {
                int row = rBase + q;
                if (row < NN) hOut[(size_t)row * 128 + col] = f2bf(fmaxf(acc[nf][q], 0.f));
            }
        }
    }
}

static inline size_t alignup(size_t x) { return (x + 255) & ~(size_t)255; }

extern "C" void kernel_launch(void* const* d_in, const int* in_sizes, int n_in,
                              void* d_out, int out_size, void* d_ws, size_t ws_size,
                              hipStream_t stream) {
    const float* x   = (const float*)d_in[0];
    const float* Ws0 = (const float*)d_in[1];
    const float* Wn0 = (const float*)d_in[2];
    const float* Ws1 = (const float*)d_in[3];
    const float* Wn1 = (const float*)d_in[4];
    const float* Ws2 = (const float*)d_in[5];
    const float* Wn2 = (const float*)d_in[6];
    const int* src   = (const int*)d_in[7];
    const int* dst   = (const int*)d_in[8];
    float* out = (float*)d_out;

    char* w = (char*)d_ws;
    size_t off = 0;
    int* row_ptr   = (int*)(w + off);   off += alignup((NN + 1) * 4);
    int* bhist     = (int*)(w + off);   off += alignup(NBK * 4);
    int* bbase     = (int*)(w + off);   off += alignup((NBK + 1) * 4);
    int* gcur      = (int*)(w + off);   off += alignup((size_t)NBK * 16 * 4);
    float* inv_deg = (float*)(w + off); off += alignup(NN * 4);
    int* csr       = (int*)(w + off);   off += alignup((size_t)NE * 4);
    unsigned* pairs = (unsigned*)(w + off); off += alignup((size_t)NE * 4);
    unsigned short* wp0 = (unsigned short*)(w + off); off += alignup(8 * 8 * 64 * 8 * 2);
    unsigned short* wp1 = (unsigned short*)(w + off); off += alignup(8 * 8 * 64 * 8 * 2);
    unsigned short* wp2 = (unsigned short*)(w + off); off += alignup(8 * 3 * 64 * 8 * 2);
    unsigned short* hA  = (unsigned short*)(w + off); off += alignup((size_t)NN * 128 * 2);
    unsigned short* hB  = (unsigned short*)(w + off); off += alignup((size_t)NN * 128 * 2);
    unsigned short* agg = (unsigned short*)(w + off); off += alignup((size_t)NN * 128 * 2);

    hipMemsetAsync(bhist, 0, NBK * 4, stream);

    cast_x<<<dim3((NN * 128 / 4 + 255) / 256), dim3(256), 0, stream>>>(x, hA, NN * 128);
    hist_buck<<<dim3((NE + 4095) / 4096), dim3(256), 0, stream>>>(dst, bhist);
    scan_buck<<<dim3(1), dim3(256), 0, stream>>>(bhist, bbase, gcur, row_ptr);
    sort_scatter<<<dim3((NE + 4095) / 4096), dim3(256), 0, stream>>>(src, dst, gcur, pairs);
    bucket_place<<<dim3(NBK), dim3(512), 0, stream>>>(pairs, bbase, row_ptr, inv_deg, csr);

    pack_w_all<<<dim3((77824 + 255) / 256), dim3(256), 0, stream>>>(
        Ws0, Wn0, Ws1, Wn1, Ws2, Wn2, wp0, wp1, wp2);

    const int aggGrid  = (NN / 2 + 3) / 4;      // 2 nodes per wave, 4 waves per block
    const int gemmGrid = (NN + 63) / 64;

    // layer 0
    aggregate<<<dim3(aggGrid), dim3(256), 0, stream>>>((const unsigned*)hA, csr, row_ptr, inv_deg, (unsigned*)agg);
    gemm_k<8, false><<<dim3(gemmGrid), dim3(256), 0, stream>>>(hA, agg, wp0, hB, nullptr);
    // layer 1
    aggregate<<<dim3(aggGrid), dim3(256), 0, stream>>>((const unsigned*)hB, csr, row_ptr, inv_deg, (unsigned*)agg);
    gemm_k<8, false><<<dim3(gemmGrid), dim3(256), 0, stream>>>(hB, agg, wp1, hA, nullptr);
    // layer 2
    aggregate<<<dim3(aggGrid), dim3(256), 0, stream>>>((const unsigned*)hA, csr, row_ptr, inv_deg, (unsigned*)agg);
    gemm_k<3, true><<<dim3(gemmGrid), dim3(256), 0, stream>>>(hA, agg, wp2, nullptr, out);
}

// Round 8
// 334.313 us; speedup vs baseline: 1.1623x; 1.1623x over previous
//
#include <hip/hip_runtime.h>
#include <hip/hip_bf16.h>

#define NN 100000
#define NE 1600000
#define NBK 391          // buckets of 256 nodes: ceil(100000/256)

typedef __attribute__((ext_vector_type(8))) short bf16x8;
typedef __attribute__((ext_vector_type(4))) float f32x4;

__device__ __forceinline__ unsigned short f2bf(float x) {
    unsigned u = __float_as_uint(x);
    return (unsigned short)((u + 0x7fffu + ((u >> 16) & 1u)) >> 16);
}
__device__ __forceinline__ float bflo(unsigned v) { return __uint_as_float(v << 16); }
__device__ __forceinline__ float bfhi(unsigned v) { return __uint_as_float(v & 0xffff0000u); }

#define ACCV(A, v) do { \
    A[0] += bflo((v).x); A[1] += bfhi((v).x); \
    A[2] += bflo((v).y); A[3] += bfhi((v).y); \
    A[4] += bflo((v).z); A[5] += bfhi((v).z); \
    A[6] += bflo((v).w); A[7] += bfhi((v).w); } while (0)

// bijective XCD swizzle (m204): block i -> contiguous chunk per XCD (8 XCDs)
__device__ __forceinline__ int swz8(int i, int nwg) {
    int q = nwg >> 3, r = nwg & 7;
    int x = i & 7, j = i >> 3;
    return (x < r) ? x * (q + 1) + j : r * (q + 1) + (x - r) * q + j;
}

// ---------------- cast x (f32) -> bf16 ----------------
__global__ void cast_x(const float* __restrict__ x, unsigned short* __restrict__ h, int n) {
    int i = (blockIdx.x * blockDim.x + threadIdx.x) * 4;
    if (i >= n) return;
    float4 v = *(const float4*)(x + i);
    unsigned out0 = ((unsigned)f2bf(v.y) << 16) | f2bf(v.x);
    unsigned out1 = ((unsigned)f2bf(v.w) << 16) | f2bf(v.z);
    *(uint2*)(h + i) = make_uint2(out0, out1);
}

// ---------------- bucket histogram (391 buckets, LDS-first) ----------------
__global__ __launch_bounds__(256) void hist_buck(const int* __restrict__ dst, int* __restrict__ bhist) {
    __shared__ int h[NBK];
    int t = threadIdx.x;
    for (int i = t; i < NBK; i += 256) h[i] = 0;
    __syncthreads();
    int base = blockIdx.x * 4096;
#pragma unroll
    for (int i = 0; i < 16; ++i) {
        int e = base + t + i * 256;
        if (e < NE) atomicAdd(&h[dst[e] >> 8], 1);
    }
    __syncthreads();
    for (int i = t; i < NBK; i += 256)
        if (h[i]) atomicAdd(&bhist[i], h[i]);
}

// ---- fused: block 0 scans buckets -> bbase/gcur/row_ptr[NN]; blocks 1.. pack weights ----
__global__ __launch_bounds__(512) void scan_pack(const int* __restrict__ bhist, int* __restrict__ bbase,
                                                 int* __restrict__ gcur, int* __restrict__ row_ptr,
                                                 const float* __restrict__ Ws0, const float* __restrict__ Wn0,
                                                 const float* __restrict__ Ws1, const float* __restrict__ Wn1,
                                                 const float* __restrict__ Ws2, const float* __restrict__ Wn2,
                                                 unsigned short* __restrict__ wp0, unsigned short* __restrict__ wp1,
                                                 unsigned short* __restrict__ wp2) {
    int t = threadIdx.x;
    if (blockIdx.x == 0) {
        __shared__ int s[512];
        int v = (t < NBK) ? bhist[t] : 0;
        s[t] = v;
        __syncthreads();
        for (int off = 1; off < 512; off <<= 1) {
            int u = (t >= off) ? s[t - off] : 0;
            __syncthreads();
            s[t] += u;
            __syncthreads();
        }
        int ex = s[t] - v;
        if (t <= NBK) bbase[t] = ex;          // bbase[NBK] == NE
        if (t < NBK) gcur[t * 16] = ex;
        if (t == 0) row_ptr[NN] = NE;
        return;
    }
    int local = (blockIdx.x - 1) * 512 + t;   // 0 .. 77823
    const float *Ws, *Wn;
    unsigned short* wp;
    int Ncols, NF;
    if (local < 32768)      { Ws = Ws0; Wn = Wn0; wp = wp0; Ncols = 128; NF = 8; }
    else if (local < 65536) { Ws = Ws1; Wn = Wn1; wp = wp1; Ncols = 128; NF = 8; local -= 32768; }
    else                    { Ws = Ws2; Wn = Wn2; wp = wp2; Ncols = 47;  NF = 3; local -= 65536; }
    int j = local & 7;
    int lane = (local >> 3) & 63;
    int fid = local >> 9;          // kstep*NF + nf
    int nf = fid % NF;
    int kstep = fid / NF;
    int k = kstep * 32 + (lane >> 4) * 8 + j;
    int n = nf * 16 + (lane & 15);
    float v = 0.f;
    if (n < Ncols) v = (k < 128) ? Ws[k * Ncols + n] : Wn[(k - 128) * Ncols + n];
    wp[local] = f2bf(v);
}

// ------- block-local counting sort; contiguous runs per (block,bucket) -------
__global__ __launch_bounds__(256) void sort_scatter(const int* __restrict__ src,
                                                    const int* __restrict__ dst,
                                                    int* __restrict__ gcur,
                                                    unsigned* __restrict__ pairs) {
    __shared__ int bcnt[NBK], gbase[NBK], lcur[NBK];
    int t = threadIdx.x;
    for (int i = t; i < NBK; i += 256) { bcnt[i] = 0; lcur[i] = 0; }
    __syncthreads();
    int base = blockIdx.x * 4096;
#pragma unroll
    for (int i = 0; i < 16; ++i) {
        int e = base + t + i * 256;
        if (e < NE) atomicAdd(&bcnt[dst[e] >> 8], 1);
    }
    __syncthreads();
    for (int i = t; i < NBK; i += 256)
        if (bcnt[i]) gbase[i] = atomicAdd(&gcur[i * 16], bcnt[i]);
    __syncthreads();
#pragma unroll
    for (int i = 0; i < 16; ++i) {
        int e = base + t + i * 256;
        if (e < NE) {
            int d = dst[e];
            int b = d >> 8;
            int p = atomicAdd(&lcur[b], 1);
            pairs[gbase[b] + p] = ((unsigned)src[e] << 8) | (unsigned)(d & 255);
        }
    }
}

// ------- per bucket (256 nodes): node hist + scan -> row_ptr/inv_deg; place -> csr -------
// csr stores src*256 (byte offset into 256B bf16 h rows) == pair & ~255u.
__global__ __launch_bounds__(256) void bucket_place(const unsigned* __restrict__ pairs,
                                                    const int* __restrict__ bbase,
                                                    int* __restrict__ row_ptr,
                                                    float* __restrict__ inv_deg,
                                                    int* __restrict__ csr) {
    __shared__ int hist[256], sc[256], cur[256];
    int b = blockIdx.x, t = threadIdx.x;
    hist[t] = 0;
    __syncthreads();
    int beg = bbase[b], end = bbase[b + 1];
    for (int i = beg + t; i < end; i += 256) atomicAdd(&hist[pairs[i] & 255u], 1);
    __syncthreads();
    int deg = hist[t];
    sc[t] = deg;
    __syncthreads();
    for (int off = 1; off < 256; off <<= 1) {
        int u = (t >= off) ? sc[t - off] : 0;
        __syncthreads();
        sc[t] += u;
        __syncthreads();
    }
    int ex = sc[t] - deg;
    int node = b * 256 + t;
    if (node < NN) {
        row_ptr[node] = beg + ex;
        inv_deg[node] = 1.0f / (float)max(deg, 1);
    }
    cur[t] = beg + ex;
    __syncthreads();
    for (int i = beg + t; i < end; i += 256) {
        unsigned p = pairs[i];
        int pos = atomicAdd(&cur[p & 255u], 1);
        csr[pos] = (int)(p & 0xFFFFFF00u);   // src * 256 bytes
    }
}

// ---- aggregate: one node per wave; 16-lane groups, dwordx4 gathers, 16 edges in flight ----
// XCD-chunked: block b -> node chunk (b&7)*3125 + (b>>3); each XCD owns 12500 contiguous nodes.
__global__ __launch_bounds__(256) void aggregate(const unsigned* __restrict__ h32,
                                                 const int* __restrict__ csr,
                                                 const int* __restrict__ row_ptr,
                                                 const float* __restrict__ inv_deg,
                                                 unsigned* __restrict__ agg32) {
    int lane = threadIdx.x & 63;
    int wave = threadIdx.x >> 6;
    int chunk = (blockIdx.x & 7) * 3125 + (blockIdx.x >> 3);
    int node = chunk * 4 + wave;               // 25000 blocks x 4 = 100000, always < NN
    int g = lane >> 4;                         // edge subgroup 0..3
    unsigned l16 = (unsigned)(lane & 15) * 16;
    const char* hb = (const char*)h32;
    int beg = row_ptr[node], end = row_ptr[node + 1];
    float acc[8];
#pragma unroll
    for (int j = 0; j < 8; ++j) acc[j] = 0.f;

    int e = beg;
    for (; e + 15 < end; e += 16) {
        int c0 = csr[e + g];
        int c1 = csr[e + 4 + g];
        int c2 = csr[e + 8 + g];
        int c3 = csr[e + 12 + g];
        uint4 v0 = *(const uint4*)(hb + (unsigned)c0 + l16);
        uint4 v1 = *(const uint4*)(hb + (unsigned)c1 + l16);
        uint4 v2 = *(const uint4*)(hb + (unsigned)c2 + l16);
        uint4 v3 = *(const uint4*)(hb + (unsigned)c3 + l16);
        ACCV(acc, v0); ACCV(acc, v1); ACCV(acc, v2); ACCV(acc, v3);
    }
    for (; e + 3 < end; e += 4) {
        int c = csr[e + g];
        uint4 v = *(const uint4*)(hb + (unsigned)c + l16);
        ACCV(acc, v);
    }
    int rem = end - e;
    if (g < rem) {
        int c = csr[e + g];
        uint4 v = *(const uint4*)(hb + (unsigned)c + l16);
        ACCV(acc, v);
    }

#pragma unroll
    for (int j = 0; j < 8; ++j) {
        acc[j] += __shfl_xor(acc[j], 16, 64);
        acc[j] += __shfl_xor(acc[j], 32, 64);
    }
    float inv = inv_deg[node];
    if (lane < 16) {
        unsigned d0 = ((unsigned)f2bf(acc[1] * inv) << 16) | f2bf(acc[0] * inv);
        unsigned d1 = ((unsigned)f2bf(acc[3] * inv) << 16) | f2bf(acc[2] * inv);
        unsigned d2 = ((unsigned)f2bf(acc[5] * inv) << 16) | f2bf(acc[4] * inv);
        unsigned d3 = ((unsigned)f2bf(acc[7] * inv) << 16) | f2bf(acc[6] * inv);
        *(uint4*)((char*)agg32 + (size_t)node * 256 + l16) = make_uint4(d0, d1, d2, d3);
    }
}

// ---------------- fused GEMM: out = h@Wself + agg@Wneigh (K=256 via packed W) ----------------
// XCD-swizzled blocks so node ranges match aggregate's producer XCD (agg rows L2-resident).
template <int NF, bool LAST>
__global__ __launch_bounds__(256) void gemm_k(const unsigned short* __restrict__ hA,
                                              const unsigned short* __restrict__ hAgg,
                                              const unsigned short* __restrict__ wpack,
                                              unsigned short* __restrict__ hOut,
                                              float* __restrict__ fOut) {
    int lane = threadIdx.x & 63;
    int wave = threadIdx.x >> 6;
    int chunk = swz8(blockIdx.x, (int)gridDim.x);
    int base = chunk * 64;
    int aRow = base + wave * 16 + (lane & 15);
    int kgrp = (lane >> 4) * 8;

    f32x4 acc[NF];
#pragma unroll
    for (int f = 0; f < NF; ++f)
#pragma unroll
        for (int q = 0; q < 4; ++q) acc[f][q] = 0.f;

    bool inb = (aRow < NN);
#pragma unroll
    for (int half = 0; half < 2; ++half) {
        const unsigned short* A = half ? hAgg : hA;
#pragma unroll
        for (int ks = 0; ks < 4; ++ks) {
            bf16x8 afrag;
            if (inb) {
                afrag = *(const bf16x8*)(A + (size_t)aRow * 128 + ks * 32 + kgrp);
            } else {
#pragma unroll
                for (int j = 0; j < 8; ++j) afrag[j] = 0;
            }
            int kstep = half * 4 + ks;
#pragma unroll
            for (int nf = 0; nf < NF; ++nf) {
                bf16x8 b = *(const bf16x8*)(wpack + (((kstep * NF + nf) * 64) + lane) * 8);
                acc[nf] = __builtin_amdgcn_mfma_f32_16x16x32_bf16(afrag, b, acc[nf], 0, 0, 0);
            }
        }
    }

    int col0 = lane & 15;
    int rBase = base + wave * 16 + (lane >> 4) * 4;
#pragma unroll
    for (int nf = 0; nf < NF; ++nf) {
        int col = nf * 16 + col0;
        if (LAST) {
            if (col < 47) {
#pragma unroll
                for (int q = 0; q < 4; ++q) {
                    int row = rBase + q;
                    if (row < NN) fOut[(size_t)row * 47 + col] = acc[nf][q];
                }
            }
        } else {
#pragma unroll
            for (int q = 0; q < 4; ++q) {
                int row = rBase + q;
                if (row < NN) hOut[(size_t)row * 128 + col] = f2bf(fmaxf(acc[nf][q], 0.f));
            }
        }
    }
}

static inline size_t alignup(size_t x) { return (x + 255) & ~(size_t)255; }

extern "C" void kernel_launch(void* const* d_in, const int* in_sizes, int n_in,
                              void* d_out, int out_size, void* d_ws, size_t ws_size,
                              hipStream_t stream) {
    const float* x   = (const float*)d_in[0];
    const float* Ws0 = (const float*)d_in[1];
    const float* Wn0 = (const float*)d_in[2];
    const float* Ws1 = (const float*)d_in[3];
    const float* Wn1 = (const float*)d_in[4];
    const float* Ws2 = (const float*)d_in[5];
    const float* Wn2 = (const float*)d_in[6];
    const int* src   = (const int*)d_in[7];
    const int* dst   = (const int*)d_in[8];
    float* out = (float*)d_out;

    char* w = (char*)d_ws;
    size_t off = 0;
    int* row_ptr   = (int*)(w + off);   off += alignup((NN + 1) * 4);
    int* bhist     = (int*)(w + off);   off += alignup(NBK * 4);
    int* bbase     = (int*)(w + off);   off += alignup((NBK + 1) * 4);
    int* gcur      = (int*)(w + off);   off += alignup((size_t)NBK * 16 * 4);
    float* inv_deg = (float*)(w + off); off += alignup(NN * 4);
    int* csr       = (int*)(w + off);   off += alignup((size_t)NE * 4);
    unsigned* pairs = (unsigned*)(w + off); off += alignup((size_t)NE * 4);
    unsigned short* wp0 = (unsigned short*)(w + off); off += alignup(8 * 8 * 64 * 8 * 2);
    unsigned short* wp1 = (unsigned short*)(w + off); off += alignup(8 * 8 * 64 * 8 * 2);
    unsigned short* wp2 = (unsigned short*)(w + off); off += alignup(8 * 3 * 64 * 8 * 2);
    unsigned short* hA  = (unsigned short*)(w + off); off += alignup((size_t)NN * 128 * 2);
    unsigned short* hB  = (unsigned short*)(w + off); off += alignup((size_t)NN * 128 * 2);
    unsigned short* agg = (unsigned short*)(w + off); off += alignup((size_t)NN * 128 * 2);

    hipMemsetAsync(bhist, 0, NBK * 4, stream);

    cast_x<<<dim3((NN * 128 / 4 + 255) / 256), dim3(256), 0, stream>>>(x, hA, NN * 128);
    hist_buck<<<dim3((NE + 4095) / 4096), dim3(256), 0, stream>>>(dst, bhist);
    scan_pack<<<dim3(153), dim3(512), 0, stream>>>(bhist, bbase, gcur, row_ptr,
                                                   Ws0, Wn0, Ws1, Wn1, Ws2, Wn2, wp0, wp1, wp2);
    sort_scatter<<<dim3((NE + 4095) / 4096), dim3(256), 0, stream>>>(src, dst, gcur, pairs);
    bucket_place<<<dim3(NBK), dim3(256), 0, stream>>>(pairs, bbase, row_ptr, inv_deg, csr);

    const int aggGrid  = NN / 4;                 // 25000 blocks, exact
    const int gemmGrid = (NN + 63) / 64;         // 1563

    // layer 0
    aggregate<<<dim3(aggGrid), dim3(256), 0, stream>>>((const unsigned*)hA, csr, row_ptr, inv_deg, (unsigned*)agg);
    gemm_k<8, false><<<dim3(gemmGrid), dim3(256), 0, stream>>>(hA, agg, wp0, hB, nullptr);
    // layer 1
    aggregate<<<dim3(aggGrid), dim3(256), 0, stream>>>((const unsigned*)hB, csr, row_ptr, inv_deg, (unsigned*)agg);
    gemm_k<8, false><<<dim3(gemmGrid), dim3(256), 0, stream>>>(hB, agg, wp1, hA, nullptr);
    // layer 2
    aggregate<<<dim3(aggGrid), dim3(256), 0, stream>>>((const unsigned*)hA, csr, row_ptr, inv_deg, (unsigned*)agg);
    gemm_k<3, true><<<dim3(gemmGrid), dim3(256), 0, stream>>>(hA, agg, wp2, nullptr, out);
}

// Round 9
// 322.403 us; speedup vs baseline: 1.2053x; 1.0369x over previous
//
#include <hip/hip_runtime.h>
#include <hip/hip_bf16.h>

#define NN 100000
#define NE 1600000
#define NBK 391          // buckets of 256 nodes: ceil(100000/256)
#define SLOT 4608        // fixed pairs capacity per bucket (Poisson(4096)+8 sigma)

typedef __attribute__((ext_vector_type(8))) short bf16x8;
typedef __attribute__((ext_vector_type(4))) float f32x4;

__device__ __forceinline__ unsigned short f2bf(float x) {
    unsigned u = __float_as_uint(x);
    return (unsigned short)((u + 0x7fffu + ((u >> 16) & 1u)) >> 16);
}
__device__ __forceinline__ float bflo(unsigned v) { return __uint_as_float(v << 16); }
__device__ __forceinline__ float bfhi(unsigned v) { return __uint_as_float(v & 0xffff0000u); }

#define ACCV(A, v) do { \
    A[0] += bflo((v).x); A[1] += bfhi((v).x); \
    A[2] += bflo((v).y); A[3] += bfhi((v).y); \
    A[4] += bflo((v).z); A[5] += bfhi((v).z); \
    A[6] += bflo((v).w); A[7] += bfhi((v).w); } while (0)

// bijective XCD swizzle (m204): block i -> contiguous chunk per XCD (8 XCDs)
__device__ __forceinline__ int swz8(int i, int nwg) {
    int q = nwg >> 3, r = nwg & 7;
    int x = i & 7, j = i >> 3;
    return (x < r) ? x * (q + 1) + j : r * (q + 1) + (x - r) * q + j;
}

// ---------------- cast x (f32) -> bf16 (XCD-chunked rows) + init gcur slots ----------------
__global__ __launch_bounds__(256) void cast_x(const float* __restrict__ x,
                                              unsigned short* __restrict__ h,
                                              int* __restrict__ gcur) {
    if (blockIdx.x == 0) {
        for (int i = threadIdx.x; i < NBK; i += 256) gcur[i * 16] = i * SLOT;
    }
    int chunk = swz8(blockIdx.x, (int)gridDim.x);
    int i = (chunk * 256 + (int)threadIdx.x) * 4;
    if (i >= NN * 128) return;
    float4 v = *(const float4*)(x + i);
    unsigned out0 = ((unsigned)f2bf(v.y) << 16) | f2bf(v.x);
    unsigned out1 = ((unsigned)f2bf(v.w) << 16) | f2bf(v.z);
    *(uint2*)(h + i) = make_uint2(out0, out1);
}

// ------- block-local counting sort into fixed bucket slots (no pre-scan needed) -------
__global__ __launch_bounds__(256) void sort_scatter(const int* __restrict__ src,
                                                    const int* __restrict__ dst,
                                                    int* __restrict__ gcur,
                                                    unsigned* __restrict__ pairs) {
    __shared__ int bcnt[NBK], gbase[NBK], lcur[NBK];
    int t = threadIdx.x;
    for (int i = t; i < NBK; i += 256) { bcnt[i] = 0; lcur[i] = 0; }
    __syncthreads();
    int base = blockIdx.x * 2048;
    int d[8];
#pragma unroll
    for (int i = 0; i < 8; ++i) {
        int e = base + t + i * 256;
        d[i] = (e < NE) ? dst[e] : -1;
        if (d[i] >= 0) atomicAdd(&bcnt[d[i] >> 8], 1);
    }
    __syncthreads();
    for (int i = t; i < NBK; i += 256)
        if (bcnt[i]) gbase[i] = atomicAdd(&gcur[i * 16], bcnt[i]);
    __syncthreads();
#pragma unroll
    for (int i = 0; i < 8; ++i) {
        if (d[i] >= 0) {
            int e = base + t + i * 256;
            int b = d[i] >> 8;
            int p = atomicAdd(&lcur[b], 1);
            pairs[gbase[b] + p] = ((unsigned)src[e] << 8) | (unsigned)(d[i] & 255);
        }
    }
}

// ---- fused: block 0 scans bucket counts -> bbase + row_ptr[NN]; blocks 1.. pack weights ----
__global__ __launch_bounds__(512) void scan_pack(const int* __restrict__ gcur, int* __restrict__ bbase,
                                                 int* __restrict__ row_ptr,
                                                 const float* __restrict__ Ws0, const float* __restrict__ Wn0,
                                                 const float* __restrict__ Ws1, const float* __restrict__ Wn1,
                                                 const float* __restrict__ Ws2, const float* __restrict__ Wn2,
                                                 unsigned short* __restrict__ wp0, unsigned short* __restrict__ wp1,
                                                 unsigned short* __restrict__ wp2) {
    int t = threadIdx.x;
    if (blockIdx.x == 0) {
        __shared__ int s[512];
        int v = (t < NBK) ? (gcur[t * 16] - t * SLOT) : 0;
        s[t] = v;
        __syncthreads();
        for (int off = 1; off < 512; off <<= 1) {
            int u = (t >= off) ? s[t - off] : 0;
            __syncthreads();
            s[t] += u;
            __syncthreads();
        }
        int ex = s[t] - v;
        if (t <= NBK) bbase[t] = ex;          // bbase[NBK] == NE
        if (t == 0) row_ptr[NN] = NE;
        return;
    }
    int local = (blockIdx.x - 1) * 512 + t;   // 0 .. 77823
    const float *Ws, *Wn;
    unsigned short* wp;
    int Ncols, NF;
    if (local < 32768)      { Ws = Ws0; Wn = Wn0; wp = wp0; Ncols = 128; NF = 8; }
    else if (local < 65536) { Ws = Ws1; Wn = Wn1; wp = wp1; Ncols = 128; NF = 8; local -= 32768; }
    else                    { Ws = Ws2; Wn = Wn2; wp = wp2; Ncols = 47;  NF = 3; local -= 65536; }
    int j = local & 7;
    int lane = (local >> 3) & 63;
    int fid = local >> 9;          // kstep*NF + nf
    int nf = fid % NF;
    int kstep = fid / NF;
    int k = kstep * 32 + (lane >> 4) * 8 + j;
    int n = nf * 16 + (lane & 15);
    float v = 0.f;
    if (n < Ncols) v = (k < 128) ? Ws[k * Ncols + n] : Wn[(k - 128) * Ncols + n];
    wp[local] = f2bf(v);
}

// ------- per bucket (256 nodes): node hist + scan -> row_ptr/inv_deg; place -> csr -------
// csr stores src*256 (byte offset into 256B bf16 h rows) == pair & ~255u.
__global__ __launch_bounds__(256) void bucket_place(const unsigned* __restrict__ pairs,
                                                    const int* __restrict__ bbase,
                                                    int* __restrict__ row_ptr,
                                                    float* __restrict__ inv_deg,
                                                    int* __restrict__ csr) {
    __shared__ int hist[256], sc[256], cur[256];
    int b = blockIdx.x, t = threadIdx.x;
    hist[t] = 0;
    __syncthreads();
    int pbeg = b * SLOT;
    int beg = bbase[b];
    int cnt = bbase[b + 1] - beg;
    for (int i = t; i < cnt; i += 256) atomicAdd(&hist[pairs[pbeg + i] & 255u], 1);
    __syncthreads();
    int deg = hist[t];
    sc[t] = deg;
    __syncthreads();
    for (int off = 1; off < 256; off <<= 1) {
        int u = (t >= off) ? sc[t - off] : 0;
        __syncthreads();
        sc[t] += u;
        __syncthreads();
    }
    int ex = sc[t] - deg;
    int node = b * 256 + t;
    if (node < NN) {
        row_ptr[node] = beg + ex;
        inv_deg[node] = 1.0f / (float)max(deg, 1);
    }
    cur[t] = beg + ex;
    __syncthreads();
    for (int i = t; i < cnt; i += 256) {
        unsigned p = pairs[pbeg + i];
        int pos = atomicAdd(&cur[p & 255u], 1);
        csr[pos] = (int)(p & 0xFFFFFF00u);   // src * 256 bytes
    }
}

// ---- aggregate: one node per wave; 16-lane groups, dwordx4 gathers, 16 edges in flight ----
// XCD-chunked: block b -> node chunk (b&7)*3125 + (b>>3); each XCD owns 12500 contiguous nodes.
__global__ __launch_bounds__(256) void aggregate(const unsigned* __restrict__ h32,
                                                 const int* __restrict__ csr,
                                                 const int* __restrict__ row_ptr,
                                                 const float* __restrict__ inv_deg,
                                                 unsigned* __restrict__ agg32) {
    int lane = threadIdx.x & 63;
    int wave = threadIdx.x >> 6;
    int chunk = (blockIdx.x & 7) * 3125 + (blockIdx.x >> 3);
    int node = chunk * 4 + wave;               // 25000 blocks x 4 = 100000, always < NN
    int g = lane >> 4;                         // edge subgroup 0..3
    unsigned l16 = (unsigned)(lane & 15) * 16;
    const char* hb = (const char*)h32;
    int beg = row_ptr[node], end = row_ptr[node + 1];
    float inv = inv_deg[node];
    float acc[8];
#pragma unroll
    for (int j = 0; j < 8; ++j) acc[j] = 0.f;

    int e = beg;
    for (; e + 15 < end; e += 16) {
        int c0 = csr[e + g];
        int c1 = csr[e + 4 + g];
        int c2 = csr[e + 8 + g];
        int c3 = csr[e + 12 + g];
        uint4 v0 = *(const uint4*)(hb + (unsigned)c0 + l16);
        uint4 v1 = *(const uint4*)(hb + (unsigned)c1 + l16);
        uint4 v2 = *(const uint4*)(hb + (unsigned)c2 + l16);
        uint4 v3 = *(const uint4*)(hb + (unsigned)c3 + l16);
        ACCV(acc, v0); ACCV(acc, v1); ACCV(acc, v2); ACCV(acc, v3);
    }
    for (; e + 3 < end; e += 4) {
        int c = csr[e + g];
        uint4 v = *(const uint4*)(hb + (unsigned)c + l16);
        ACCV(acc, v);
    }
    int rem = end - e;
    if (g < rem) {
        int c = csr[e + g];
        uint4 v = *(const uint4*)(hb + (unsigned)c + l16);
        ACCV(acc, v);
    }

#pragma unroll
    for (int j = 0; j < 8; ++j) {
        acc[j] += __shfl_xor(acc[j], 16, 64);
        acc[j] += __shfl_xor(acc[j], 32, 64);
    }
    if (lane < 16) {
        unsigned d0 = ((unsigned)f2bf(acc[1] * inv) << 16) | f2bf(acc[0] * inv);
        unsigned d1 = ((unsigned)f2bf(acc[3] * inv) << 16) | f2bf(acc[2] * inv);
        unsigned d2 = ((unsigned)f2bf(acc[5] * inv) << 16) | f2bf(acc[4] * inv);
        unsigned d3 = ((unsigned)f2bf(acc[7] * inv) << 16) | f2bf(acc[6] * inv);
        *(uint4*)((char*)agg32 + (size_t)node * 256 + l16) = make_uint4(d0, d1, d2, d3);
    }
}

// ---------------- fused GEMM: out = h@Wself + agg@Wneigh (K=256 via packed W) ----------------
// XCD-swizzled blocks so node ranges match aggregate's producer XCD (agg rows L2-resident).
template <int NF, bool LAST>
__global__ __launch_bounds__(256) void gemm_k(const unsigned short* __restrict__ hA,
                                              const unsigned short* __restrict__ hAgg,
                                              const unsigned short* __restrict__ wpack,
                                              unsigned short* __restrict__ hOut,
                                              float* __restrict__ fOut) {
    int lane = threadIdx.x & 63;
    int wave = threadIdx.x >> 6;
    int chunk = swz8(blockIdx.x, (int)gridDim.x);
    int base = chunk * 64;
    int aRow = base + wave * 16 + (lane & 15);
    int kgrp = (lane >> 4) * 8;

    f32x4 acc[NF];
#pragma unroll
    for (int f = 0; f < NF; ++f)
#pragma unroll
        for (int q = 0; q < 4; ++q) acc[f][q] = 0.f;

    bool inb = (aRow < NN);
#pragma unroll
    for (int half = 0; half < 2; ++half) {
        const unsigned short* A = half ? hAgg : hA;
#pragma unroll
        for (int ks = 0; ks < 4; ++ks) {
            bf16x8 afrag;
            if (inb) {
                afrag = *(const bf16x8*)(A + (size_t)aRow * 128 + ks * 32 + kgrp);
            } else {
#pragma unroll
                for (int j = 0; j < 8; ++j) afrag[j] = 0;
            }
            int kstep = half * 4 + ks;
#pragma unroll
            for (int nf = 0; nf < NF; ++nf) {
                bf16x8 b = *(const bf16x8*)(wpack + (((kstep * NF + nf) * 64) + lane) * 8);
                acc[nf] = __builtin_amdgcn_mfma_f32_16x16x32_bf16(afrag, b, acc[nf], 0, 0, 0);
            }
        }
    }

    int col0 = lane & 15;
    int rBase = base + wave * 16 + (lane >> 4) * 4;
#pragma unroll
    for (int nf = 0; nf < NF; ++nf) {
        int col = nf * 16 + col0;
        if (LAST) {
            if (col < 47) {
#pragma unroll
                for (int q = 0; q < 4; ++q) {
                    int row = rBase + q;
                    if (row < NN) fOut[(size_t)row * 47 + col] = acc[nf][q];
                }
            }
        } else {
#pragma unroll
            for (int q = 0; q < 4; ++q) {
                int row = rBase + q;
                if (row < NN) hOut[(size_t)row * 128 + col] = f2bf(fmaxf(acc[nf][q], 0.f));
            }
        }
    }
}

static inline size_t alignup(size_t x) { return (x + 255) & ~(size_t)255; }

extern "C" void kernel_launch(void* const* d_in, const int* in_sizes, int n_in,
                              void* d_out, int out_size, void* d_ws, size_t ws_size,
                              hipStream_t stream) {
    const float* x   = (const float*)d_in[0];
    const float* Ws0 = (const float*)d_in[1];
    const float* Wn0 = (const float*)d_in[2];
    const float* Ws1 = (const float*)d_in[3];
    const float* Wn1 = (const float*)d_in[4];
    const float* Ws2 = (const float*)d_in[5];
    const float* Wn2 = (const float*)d_in[6];
    const int* src   = (const int*)d_in[7];
    const int* dst   = (const int*)d_in[8];
    float* out = (float*)d_out;

    char* w = (char*)d_ws;
    size_t off = 0;
    int* row_ptr   = (int*)(w + off);   off += alignup((NN + 1) * 4);
    int* bbase     = (int*)(w + off);   off += alignup((NBK + 1) * 4);
    int* gcur      = (int*)(w + off);   off += alignup((size_t)NBK * 16 * 4);
    float* inv_deg = (float*)(w + off); off += alignup(NN * 4);
    int* csr       = (int*)(w + off);   off += alignup((size_t)NE * 4);
    unsigned* pairs = (unsigned*)(w + off); off += alignup((size_t)NBK * SLOT * 4);
    unsigned short* wp0 = (unsigned short*)(w + off); off += alignup(8 * 8 * 64 * 8 * 2);
    unsigned short* wp1 = (unsigned short*)(w + off); off += alignup(8 * 8 * 64 * 8 * 2);
    unsigned short* wp2 = (unsigned short*)(w + off); off += alignup(8 * 3 * 64 * 8 * 2);
    unsigned short* hA  = (unsigned short*)(w + off); off += alignup((size_t)NN * 128 * 2);
    unsigned short* hB  = (unsigned short*)(w + off); off += alignup((size_t)NN * 128 * 2);
    unsigned short* agg = (unsigned short*)(w + off); off += alignup((size_t)NN * 128 * 2);

    cast_x<<<dim3((NN * 128 / 4 + 255) / 256), dim3(256), 0, stream>>>(x, hA, gcur);
    sort_scatter<<<dim3((NE + 2047) / 2048), dim3(256), 0, stream>>>(src, dst, gcur, pairs);
    scan_pack<<<dim3(153), dim3(512), 0, stream>>>(gcur, bbase, row_ptr,
                                                   Ws0, Wn0, Ws1, Wn1, Ws2, Wn2, wp0, wp1, wp2);
    bucket_place<<<dim3(NBK), dim3(256), 0, stream>>>(pairs, bbase, row_ptr, inv_deg, csr);

    const int aggGrid  = NN / 4;                 // 25000 blocks, exact
    const int gemmGrid = (NN + 63) / 64;         // 1563

    // layer 0
    aggregate<<<dim3(aggGrid), dim3(256), 0, stream>>>((const unsigned*)hA, csr, row_ptr, inv_deg, (unsigned*)agg);
    gemm_k<8, false><<<dim3(gemmGrid), dim3(256), 0, stream>>>(hA, agg, wp0, hB, nullptr);
    // layer 1
    aggregate<<<dim3(aggGrid), dim3(256), 0, stream>>>((const unsigned*)hB, csr, row_ptr, inv_deg, (unsigned*)agg);
    gemm_k<8, false><<<dim3(gemmGrid), dim3(256), 0, stream>>>(hB, agg, wp1, hA, nullptr);
    // layer 2
    aggregate<<<dim3(aggGrid), dim3(256), 0, stream>>>((const unsigned*)hA, csr, row_ptr, inv_deg, (unsigned*)agg);
    gemm_k<3, true><<<dim3(gemmGrid), dim3(256), 0, stream>>>(hA, agg, wp2, nullptr, out);
}

// Round 10
// 322.005 us; speedup vs baseline: 1.2068x; 1.0012x over previous
//
#include <hip/hip_runtime.h>
#include <hip/hip_bf16.h>

#define NN 100000
#define NE 1600000
#define NBK 391          // buckets of 256 nodes: ceil(100000/256)
#define SLOT 4608        // fixed pairs capacity per bucket (Poisson(4096)+8 sigma)

typedef __attribute__((ext_vector_type(8))) short bf16x8;
typedef __attribute__((ext_vector_type(4))) float f32x4;
typedef __attribute__((ext_vector_type(2))) float f32x2;

__device__ __forceinline__ unsigned short f2bf(float x) {
    unsigned u = __float_as_uint(x);
    return (unsigned short)((u + 0x7fffu + ((u >> 16) & 1u)) >> 16);
}
__device__ __forceinline__ f32x2 up2(unsigned v) {
    f32x2 r;
    r[0] = __uint_as_float(v << 16);
    r[1] = __uint_as_float(v & 0xffff0000u);
    return r;
}
// accumulate one 16B gather (4 dwords = 8 bf16 features) into 4 packed-f32 accumulators
#define ACC2(A, v) do { \
    A[0] += up2((v).x); A[1] += up2((v).y); A[2] += up2((v).z); A[3] += up2((v).w); } while (0)

// bijective XCD swizzle (m204): block i -> contiguous chunk per XCD (8 XCDs)
__device__ __forceinline__ int swz8(int i, int nwg) {
    int q = nwg >> 3, r = nwg & 7;
    int x = i & 7, j = i >> 3;
    return (x < r) ? x * (q + 1) + j : r * (q + 1) + (x - r) * q + j;
}

// ---- prep: blocks [0,12500) cast x->bf16 (XCD-chunked); blocks [12500,12804) pack weights;
//      block 12500 additionally inits gcur bucket cursors ----
__global__ __launch_bounds__(256) void prep(const float* __restrict__ x,
                                            unsigned short* __restrict__ h,
                                            int* __restrict__ gcur,
                                            const float* __restrict__ Ws0, const float* __restrict__ Wn0,
                                            const float* __restrict__ Ws1, const float* __restrict__ Wn1,
                                            const float* __restrict__ Ws2, const float* __restrict__ Wn2,
                                            unsigned short* __restrict__ wp0, unsigned short* __restrict__ wp1,
                                            unsigned short* __restrict__ wp2) {
    int b = blockIdx.x;
    if (b < 12500) {
        int chunk = swz8(b, 12500);
        int i = (chunk * 256 + (int)threadIdx.x) * 4;   // < NN*128 always (12500*1024 exact)
        float4 v = *(const float4*)(x + i);
        unsigned out0 = ((unsigned)f2bf(v.y) << 16) | f2bf(v.x);
        unsigned out1 = ((unsigned)f2bf(v.w) << 16) | f2bf(v.z);
        *(uint2*)(h + i) = make_uint2(out0, out1);
        return;
    }
    int pb = b - 12500;
    if (pb == 0) {
        for (int i = threadIdx.x; i < NBK; i += 256) gcur[i * 16] = i * SLOT;
    }
    int local = pb * 256 + (int)threadIdx.x;   // 0 .. 77823 exact (304 blocks)
    const float *Ws, *Wn;
    unsigned short* wp;
    int Ncols, NF;
    if (local < 32768)      { Ws = Ws0; Wn = Wn0; wp = wp0; Ncols = 128; NF = 8; }
    else if (local < 65536) { Ws = Ws1; Wn = Wn1; wp = wp1; Ncols = 128; NF = 8; local -= 32768; }
    else                    { Ws = Ws2; Wn = Wn2; wp = wp2; Ncols = 47;  NF = 3; local -= 65536; }
    int j = local & 7;
    int lane = (local >> 3) & 63;
    int fid = local >> 9;          // kstep*NF + nf
    int nf = fid % NF;
    int kstep = fid / NF;
    int k = kstep * 32 + (lane >> 4) * 8 + j;
    int n = nf * 16 + (lane & 15);
    float v = 0.f;
    if (n < Ncols) v = (k < 128) ? Ws[k * Ncols + n] : Wn[(k - 128) * Ncols + n];
    wp[local] = f2bf(v);
}

// ------- block-local counting sort into fixed bucket slots (no pre-scan needed) -------
__global__ __launch_bounds__(256) void sort_scatter(const int* __restrict__ src,
                                                    const int* __restrict__ dst,
                                                    int* __restrict__ gcur,
                                                    unsigned* __restrict__ pairs) {
    __shared__ int bcnt[NBK], gbase[NBK], lcur[NBK];
    int t = threadIdx.x;
    for (int i = t; i < NBK; i += 256) { bcnt[i] = 0; lcur[i] = 0; }
    __syncthreads();
    int base = blockIdx.x * 2048;
    int d[8];
#pragma unroll
    for (int i = 0; i < 8; ++i) {
        int e = base + t + i * 256;
        d[i] = (e < NE) ? dst[e] : -1;
        if (d[i] >= 0) atomicAdd(&bcnt[d[i] >> 8], 1);
    }
    __syncthreads();
    for (int i = t; i < NBK; i += 256)
        if (bcnt[i]) gbase[i] = atomicAdd(&gcur[i * 16], bcnt[i]);
    __syncthreads();
#pragma unroll
    for (int i = 0; i < 8; ++i) {
        if (d[i] >= 0) {
            int e = base + t + i * 256;
            int b = d[i] >> 8;
            int p = atomicAdd(&lcur[b], 1);
            pairs[gbase[b] + p] = ((unsigned)src[e] << 8) | (unsigned)(d[i] & 255);
        }
    }
}

// ------- per bucket (256 nodes): self-computed prefix, node hist + scan -> row_ptr/inv_deg,
//         place edges -> csr (stores src*256 byte offsets) -------
__global__ __launch_bounds__(256) void bucket_place(const unsigned* __restrict__ pairs,
                                                    const int* __restrict__ gcur,
                                                    int* __restrict__ row_ptr,
                                                    float* __restrict__ inv_deg,
                                                    int* __restrict__ csr) {
    __shared__ int cnts[NBK];
    __shared__ int red[256];
    __shared__ int hist[256], sc[256], cur[256];
    int b = blockIdx.x, t = threadIdx.x;
    for (int i = t; i < NBK; i += 256) cnts[i] = gcur[i * 16] - i * SLOT;
    hist[t] = 0;
    __syncthreads();
    // exclusive prefix for this bucket: sum cnts[0..b)
    int part = 0;
    for (int i = t; i < b; i += 256) part += cnts[i];
    red[t] = part;
    __syncthreads();
    for (int off = 128; off > 0; off >>= 1) {
        if (t < off) red[t] += red[t + off];
        __syncthreads();
    }
    int beg = red[0];
    int cnt = cnts[b];
    int pbeg = b * SLOT;
    for (int i = t; i < cnt; i += 256) atomicAdd(&hist[pairs[pbeg + i] & 255u], 1);
    __syncthreads();
    int deg = hist[t];
    sc[t] = deg;
    __syncthreads();
    for (int off = 1; off < 256; off <<= 1) {
        int u = (t >= off) ? sc[t - off] : 0;
        __syncthreads();
        sc[t] += u;
        __syncthreads();
    }
    int ex = sc[t] - deg;
    int node = b * 256 + t;
    if (node < NN) {
        row_ptr[node] = beg + ex;
        inv_deg[node] = 1.0f / (float)max(deg, 1);
    }
    if (b == NBK - 1 && t == 0) row_ptr[NN] = beg + cnt;   // == NE
    cur[t] = beg + ex;
    __syncthreads();
    for (int i = t; i < cnt; i += 256) {
        unsigned p = pairs[pbeg + i];
        int pos = atomicAdd(&cur[p & 255u], 1);
        csr[pos] = (int)(p & 0xFFFFFF00u);   // src * 256 bytes
    }
}

// ---- aggregate: one node per wave; 16-lane groups, dwordx4 gathers, 16 edges in flight ----
// XCD-chunked: block b -> node chunk (b&7)*3125 + (b>>3); each XCD owns 12500 contiguous nodes.
// Accumulators are packed float2 (v_pk_add_f32 candidate).
__global__ __launch_bounds__(256) void aggregate(const unsigned* __restrict__ h32,
                                                 const int* __restrict__ csr,
                                                 const int* __restrict__ row_ptr,
                                                 const float* __restrict__ inv_deg,
                                                 unsigned* __restrict__ agg32) {
    int lane = threadIdx.x & 63;
    int wave = threadIdx.x >> 6;
    int chunk = (blockIdx.x & 7) * 3125 + (blockIdx.x >> 3);
    int node = chunk * 4 + wave;               // 25000 blocks x 4 = 100000, always < NN
    int g = lane >> 4;                         // edge subgroup 0..3
    unsigned l16 = (unsigned)(lane & 15) * 16;
    const char* hb = (const char*)h32;
    int beg = row_ptr[node], end = row_ptr[node + 1];
    float inv = inv_deg[node];
    f32x2 acc[4];
#pragma unroll
    for (int j = 0; j < 4; ++j) { acc[j][0] = 0.f; acc[j][1] = 0.f; }

    int e = beg;
    for (; e + 15 < end; e += 16) {
        int c0 = csr[e + g];
        int c1 = csr[e + 4 + g];
        int c2 = csr[e + 8 + g];
        int c3 = csr[e + 12 + g];
        uint4 v0 = *(const uint4*)(hb + (unsigned)c0 + l16);
        uint4 v1 = *(const uint4*)(hb + (unsigned)c1 + l16);
        uint4 v2 = *(const uint4*)(hb + (unsigned)c2 + l16);
        uint4 v3 = *(const uint4*)(hb + (unsigned)c3 + l16);
        ACC2(acc, v0); ACC2(acc, v1); ACC2(acc, v2); ACC2(acc, v3);
    }
    for (; e + 3 < end; e += 4) {
        int c = csr[e + g];
        uint4 v = *(const uint4*)(hb + (unsigned)c + l16);
        ACC2(acc, v);
    }
    int rem = end - e;
    if (g < rem) {
        int c = csr[e + g];
        uint4 v = *(const uint4*)(hb + (unsigned)c + l16);
        ACC2(acc, v);
    }

#pragma unroll
    for (int j = 0; j < 4; ++j) {
#pragma unroll
        for (int k = 0; k < 2; ++k) {
            float s = acc[j][k];
            s += __shfl_xor(s, 16, 64);
            s += __shfl_xor(s, 32, 64);
            acc[j][k] = s;
        }
    }
    if (lane < 16) {
        unsigned d0 = ((unsigned)f2bf(acc[0][1] * inv) << 16) | f2bf(acc[0][0] * inv);
        unsigned d1 = ((unsigned)f2bf(acc[1][1] * inv) << 16) | f2bf(acc[1][0] * inv);
        unsigned d2 = ((unsigned)f2bf(acc[2][1] * inv) << 16) | f2bf(acc[2][0] * inv);
        unsigned d3 = ((unsigned)f2bf(acc[3][1] * inv) << 16) | f2bf(acc[3][0] * inv);
        *(uint4*)((char*)agg32 + (size_t)node * 256 + l16) = make_uint4(d0, d1, d2, d3);
    }
}

// ---------------- fused GEMM: out = h@Wself + agg@Wneigh (K=256 via packed W) ----------------
// XCD-swizzled blocks so node ranges match aggregate's producer XCD (agg rows L2-resident).
template <int NF, bool LAST>
__global__ __launch_bounds__(256) void gemm_k(const unsigned short* __restrict__ hA,
                                              const unsigned short* __restrict__ hAgg,
                                              const unsigned short* __restrict__ wpack,
                                              unsigned short* __restrict__ hOut,
                                              float* __restrict__ fOut) {
    int lane = threadIdx.x & 63;
    int wave = threadIdx.x >> 6;
    int chunk = swz8(blockIdx.x, (int)gridDim.x);
    int base = chunk * 64;
    int aRow = base + wave * 16 + (lane & 15);
    int kgrp = (lane >> 4) * 8;

    f32x4 acc[NF];
#pragma unroll
    for (int f = 0; f < NF; ++f)
#pragma unroll
        for (int q = 0; q < 4; ++q) acc[f][q] = 0.f;

    bool inb = (aRow < NN);
#pragma unroll
    for (int half = 0; half < 2; ++half) {
        const unsigned short* A = half ? hAgg : hA;
#pragma unroll
        for (int ks = 0; ks < 4; ++ks) {
            bf16x8 afrag;
            if (inb) {
                afrag = *(const bf16x8*)(A + (size_t)aRow * 128 + ks * 32 + kgrp);
            } else {
#pragma unroll
                for (int j = 0; j < 8; ++j) afrag[j] = 0;
            }
            int kstep = half * 4 + ks;
#pragma unroll
            for (int nf = 0; nf < NF; ++nf) {
                bf16x8 b = *(const bf16x8*)(wpack + (((kstep * NF + nf) * 64) + lane) * 8);
                acc[nf] = __builtin_amdgcn_mfma_f32_16x16x32_bf16(afrag, b, acc[nf], 0, 0, 0);
            }
        }
    }

    int col0 = lane & 15;
    int rBase = base + wave * 16 + (lane >> 4) * 4;
#pragma unroll
    for (int nf = 0; nf < NF; ++nf) {
        int col = nf * 16 + col0;
        if (LAST) {
            if (col < 47) {
#pragma unroll
                for (int q = 0; q < 4; ++q) {
                    int row = rBase + q;
                    if (row < NN) fOut[(size_t)row * 47 + col] = acc[nf][q];
                }
            }
        } else {
#pragma unroll
            for (int q = 0; q < 4; ++q) {
                int row = rBase + q;
                if (row < NN) hOut[(size_t)row * 128 + col] = f2bf(fmaxf(acc[nf][q], 0.f));
            }
        }
    }
}

static inline size_t alignup(size_t x) { return (x + 255) & ~(size_t)255; }

extern "C" void kernel_launch(void* const* d_in, const int* in_sizes, int n_in,
                              void* d_out, int out_size, void* d_ws, size_t ws_size,
                              hipStream_t stream) {
    const float* x   = (const float*)d_in[0];
    const float* Ws0 = (const float*)d_in[1];
    const float* Wn0 = (const float*)d_in[2];
    const float* Ws1 = (const float*)d_in[3];
    const float* Wn1 = (const float*)d_in[4];
    const float* Ws2 = (const float*)d_in[5];
    const float* Wn2 = (const float*)d_in[6];
    const int* src   = (const int*)d_in[7];
    const int* dst   = (const int*)d_in[8];
    float* out = (float*)d_out;

    char* w = (char*)d_ws;
    size_t off = 0;
    int* row_ptr   = (int*)(w + off);   off += alignup((NN + 1) * 4);
    int* gcur      = (int*)(w + off);   off += alignup((size_t)NBK * 16 * 4);
    float* inv_deg = (float*)(w + off); off += alignup(NN * 4);
    int* csr       = (int*)(w + off);   off += alignup((size_t)NE * 4);
    unsigned* pairs = (unsigned*)(w + off); off += alignup((size_t)NBK * SLOT * 4);
    unsigned short* wp0 = (unsigned short*)(w + off); off += alignup(8 * 8 * 64 * 8 * 2);
    unsigned short* wp1 = (unsigned short*)(w + off); off += alignup(8 * 8 * 64 * 8 * 2);
    unsigned short* wp2 = (unsigned short*)(w + off); off += alignup(8 * 3 * 64 * 8 * 2);
    unsigned short* hA  = (unsigned short*)(w + off); off += alignup((size_t)NN * 128 * 2);
    unsigned short* hB  = (unsigned short*)(w + off); off += alignup((size_t)NN * 128 * 2);
    unsigned short* agg = (unsigned short*)(w + off); off += alignup((size_t)NN * 128 * 2);

    prep<<<dim3(12804), dim3(256), 0, stream>>>(x, hA, gcur,
                                                Ws0, Wn0, Ws1, Wn1, Ws2, Wn2, wp0, wp1, wp2);
    sort_scatter<<<dim3((NE + 2047) / 2048), dim3(256), 0, stream>>>(src, dst, gcur, pairs);
    bucket_place<<<dim3(NBK), dim3(256), 0, stream>>>(pairs, gcur, row_ptr, inv_deg, csr);

    const int aggGrid  = NN / 4;                 // 25000 blocks, exact
    const int gemmGrid = (NN + 63) / 64;         // 1563

    // layer 0
    aggregate<<<dim3(aggGrid), dim3(256), 0, stream>>>((const unsigned*)hA, csr, row_ptr, inv_deg, (unsigned*)agg);
    gemm_k<8, false><<<dim3(gemmGrid), dim3(256), 0, stream>>>(hA, agg, wp0, hB, nullptr);
    // layer 1
    aggregate<<<dim3(aggGrid), dim3(256), 0, stream>>>((const unsigned*)hB, csr, row_ptr, inv_deg, (unsigned*)agg);
    gemm_k<8, false><<<dim3(gemmGrid), dim3(256), 0, stream>>>(hB, agg, wp1, hA, nullptr);
    // layer 2
    aggregate<<<dim3(aggGrid), dim3(256), 0, stream>>>((const unsigned*)hA, csr, row_ptr, inv_deg, (unsigned*)agg);
    gemm_k<3, true><<<dim3(gemmGrid), dim3(256), 0, stream>>>(hA, agg, wp2, nullptr, out);
}